// Round 7
// baseline (163.284 us; speedup 1.0000x reference)
//
#include <hip/hip_runtime.h>
#include <math.h>

// v15: v14 (162us harness, best) + ONE change: anti-phase skew between the
// two CU-coresident blocks. Analysis: each SIMD hosts 1 wave from each of 2
// blocks running IDENTICAL code launched together -> phase-locked -> both
// stall at the same lgkm/barrier points; ~70% of the eval wall is stall that
// dual-residency fails to cover. Fix: blocks with ((bid ^ bid>>8)&1)==1
// sleep ~8K cycles at entry (half an eval). The XOR bit differs within a
// CU-pair under both dispatch models (consecutive-ID pairing: bit0;
// XCD-stride-256 pairing: bit8). Skew persists (identical per-eval length),
// so block A's latency chains run under block B's throughput phases -- and
// setprio's solve-priority finally has desynced waves to arbitrate (m191
// regime). Correctness-neutral pure delay. Everything else byte-identical
// to v14 (passing, absmax 0.0156).

typedef _Float16 f16;
typedef _Float16 f16x2 __attribute__((ext_vector_type(2)));
typedef _Float16 f16x4 __attribute__((ext_vector_type(4)));
typedef _Float16 f16x8 __attribute__((ext_vector_type(8)));
typedef __fp16 h16x2 __attribute__((ext_vector_type(2)));   // builtin return type
typedef float f32x2 __attribute__((ext_vector_type(2)));
typedef float f32x4 __attribute__((ext_vector_type(4)));
typedef float f32x16 __attribute__((ext_vector_type(16)));

#define SAG_P 392   // f16 point stride; row stride 24, aug col at 16
#define SZ_P  36    // f32
#define SH_P  72    // f16
#define SW_P  20    // f32
#define SWP_C 20    // f32 stride of sWp per (wave,point)

__device__ __forceinline__ float fastTanh(float x) {
    float e = exp2f(x * 2.885390081777927f);
    return 1.0f - 2.0f * __builtin_amdgcn_rcpf(1.0f + e);
}

__device__ __forceinline__ f16x2 pk2(float a, float b) {
    h16x2 p = __builtin_amdgcn_cvt_pkrtz(a, b);
    return __builtin_bit_cast(f16x2, p);
}

typedef union { f16x4 v4; f16x2 v2[2]; } u16x4;
typedef union { f16x8 v8; f16x2 v2[4]; int i32[4]; } u16x8;

// broadcast lane K of each 16-lane row via DPP row_newbcast (VALU, no DS)
template<int K>
__device__ __forceinline__ float bcf(float x) {
    int v = __builtin_amdgcn_mov_dpp(__builtin_bit_cast(int, x),
                                     0x150 | K, 0xf, 0xf, false);
    return __builtin_bit_cast(float, v);
}

// Paired Gauss-Jordan elimination: two independent systems interleaved at
// source level so their serial bcast->rcp->mul->fma chains overlap.
// (compiler auto-fuses mov_dpp + fmac into v_fmac_f32_dpp -- keep VOP2 form)
template<int K>
__device__ __forceinline__ void fe_all2(float (&R0)[17], float (&R1)[17],
                                        const int i16, float &inv0, float &inv1) {
    if constexpr (K < 16) {
        float p0 = bcf<K>(R0[K]);
        float p1 = bcf<K>(R1[K]);
        float pi0 = __builtin_amdgcn_rcpf(p0);
        float pi1 = __builtin_amdgcn_rcpf(p1);
        if (i16 == K) { inv0 = pi0; inv1 = pi1; }
        float f0 = (i16 == K) ? 0.0f : R0[K] * pi0;
        float f1 = (i16 == K) ? 0.0f : R1[K] * pi1;
        #pragma unroll
        for (int j = K + 1; j <= 16; ++j) {
            float v0 = bcf<K>(R0[j]);
            float v1 = bcf<K>(R1[j]);
            R0[j] -= f0 * v0;
            R1[j] -= f1 * v1;
        }
        fe_all2<K + 1>(R0, R1, i16, inv0, inv1);
    }
}

__global__ __launch_bounds__(256, 1)
void geo_kernel(const float* __restrict__ zin, const float* __restrict__ tg,
                const float* __restrict__ W1g, const float* __restrict__ b1g,
                const float* __restrict__ W2g, const float* __restrict__ b2g,
                const int* __restrict__ nsg, float* __restrict__ outg, int B)
{
    __shared__ __align__(16) f16   sAG[2][16 * SAG_P];      // A, then G (+aug)
    __shared__ __align__(16) f16   sHT[2][16 * SH_P];       // h, later t
    __shared__ __align__(16) float sZI[2][16 * SZ_P];
    __shared__ __align__(16) float sKV[2][16 * SW_P];
    __shared__ __align__(16) float sWp[2][4 * 16 * SWP_C];  // w partials per wave

    // ---- anti-phase skew: half an eval (~8K cy) for one block of each
    // CU-coresident pair. XOR of bit0 and bit8 differs within the pair
    // under both consecutive-ID and XCD-stride-256 dispatch models.
    if ((blockIdx.x ^ (blockIdx.x >> 8)) & 1) {
        __builtin_amdgcn_s_sleep(64);
        __builtin_amdgcn_s_sleep(63);
    }

    const int tid = threadIdx.x;
    const int w = tid >> 6;
    const int l = tid & 63;
    const int i16 = l & 15, q4 = l >> 4, h2 = l >> 5, sc = q4 & 1;

    // ---------------- hoisted weight fragments (quarter per wave) ----------
    f16x8 w2a[4][2];   // A-stage A-op: W2^T[e=i16+16(4w+t)][k=8q4+j+32ch]
    #pragma unroll
    for (int t = 0; t < 4; ++t)
        #pragma unroll
        for (int ch = 0; ch < 2; ++ch)
            #pragma unroll
            for (int j = 0; j < 8; ++j)
                w2a[t][ch][j] = (f16)W2g[(8*q4 + j + 32*ch)*256 + i16 + 16*(4*w + t)];

    f16x8 w2r[8];      // r-stage A-op: W2[n=i16+16w][e=8q4+j+32ch]
    #pragma unroll
    for (int ch = 0; ch < 8; ++ch)
        #pragma unroll
        for (int j = 0; j < 8; ++j)
            w2r[ch][j] = (f16)W2g[(i16 + 16*w)*256 + 8*q4 + j + 32*ch];

    f16x8 w1h;         // H-stage A-op: W1^T[n=i16+16w][x=8q4+j], zero-pad k>=16
    #pragma unroll
    for (int j = 0; j < 8; ++j) {
        int k = 8*q4 + j;
        w1h[j] = (k < 16) ? (f16)W1g[k*64 + i16 + 16*w] : (f16)0.0f;
    }

    f16x8 w1q[2];      // q-stage A-op: W1[i=i16][n=8q4+j+32ch]
    #pragma unroll
    for (int ch = 0; ch < 2; ++ch)
        #pragma unroll
        for (int j = 0; j < 8; ++j)
            w1q[ch][j] = (f16)W1g[i16*64 + 8*q4 + j + 32*ch];

    float b2v[4][4];   // b2[e = 16*(4w+t) + 4q4+reg]
    #pragma unroll
    for (int t = 0; t < 4; ++t)
        #pragma unroll
        for (int reg = 0; reg < 4; ++reg)
            b2v[t][reg] = b2g[16*(4*w + t) + 4*q4 + reg];
    float b1v[4];      // b1[n = 16w + 4q4+reg]
    #pragma unroll
    for (int reg = 0; reg < 4; ++reg) b1v[reg] = b1g[16*w + 4*q4 + reg];

    // ---------------- RK4 state: thread owns points (g,tid>>4) ------------
    const int pb = blockIdx.x * 32;
    const int p_cmb = tid >> 4;            // == 4w + q4
    const int g16 = tid & 15;
    f32x2 zc[2], ar[2];
    #pragma unroll
    for (int g = 0; g < 2; ++g) {
        int pl = pb + 16*g + p_cmb;
        int pg = (pl < B) ? pl : (B - 1);
        zc[g] = *(const f32x2*)&zin[pg*32 + 2*g16];
        *(f32x2*)&sZI[g][p_cmb*SZ_P + 2*g16] = zc[g];
    }
    __syncthreads();

    const float tv = tg[0];
    const int nst = nsg[0];
    const float dt = tv / (float)nst;

    const int xmask = (q4 >= 2) ? 0 : -1;

    #pragma unroll 1
    for (int st = 0; st < nst; ++st) {
        #pragma unroll 1
        for (int s = 0; s < 4; ++s) {
            float dreg[2][4];
            // ======== X-load + H, both sets ========
            #pragma unroll
            for (int g = 0; g < 2; ++g) {
                u16x8 xf;
                {
                    f32x4 xa = *(const f32x4*)&sZI[g][i16*SZ_P + 8*sc];
                    f32x4 xb = *(const f32x4*)&sZI[g][i16*SZ_P + 8*sc + 4];
                    xf.v2[0] = pk2(xa[0], xa[1]);
                    xf.v2[1] = pk2(xa[2], xa[3]);
                    xf.v2[2] = pk2(xb[0], xb[1]);
                    xf.v2[3] = pk2(xb[2], xb[3]);
                    #pragma unroll
                    for (int jp = 0; jp < 4; ++jp) xf.i32[jp] &= xmask;
                }
                f32x4 hc = {0.f, 0.f, 0.f, 0.f};
                hc = __builtin_amdgcn_mfma_f32_16x16x32_f16(w1h, xf.v8, hc, 0, 0, 0);
                float hv[4];
                #pragma unroll
                for (int reg = 0; reg < 4; ++reg) {
                    hv[reg] = fastTanh(hc[reg] + b1v[reg]);
                    dreg[g][reg] = hv[reg]*hv[reg] - 1.0f;
                }
                u16x4 hv4;
                hv4.v2[0] = pk2(hv[0], hv[1]);
                hv4.v2[1] = pk2(hv[2], hv[3]);
                *(f16x4*)&sHT[g][i16*SH_P + 16*w + 4*q4] = hv4.v4;
            }
            __syncthreads();   // B1: h ready
            // ======== A stage, both sets ========
            #pragma unroll
            for (int g = 0; g < 2; ++g) {
                f32x4 vA = *(const f32x4*)&sZI[g][i16*SZ_P + 16 + 4*w];
                f16x8 hf0 = *(const f16x8*)&sHT[g][i16*SH_P + 8*q4];
                f16x8 hf1 = *(const f16x8*)&sHT[g][i16*SH_P + 8*q4 + 32];
                float pw[4] = {0.f, 0.f, 0.f, 0.f};
                #pragma unroll
                for (int t = 0; t < 4; ++t) {
                    f32x4 ac = {0.f, 0.f, 0.f, 0.f};
                    ac = __builtin_amdgcn_mfma_f32_16x16x32_f16(w2a[t][0], hf0, ac, 0, 0, 0);
                    ac = __builtin_amdgcn_mfma_f32_16x16x32_f16(w2a[t][1], hf1, ac, 0, 0, 0);
                    float a0 = ac[0] + b2v[t][0], a1 = ac[1] + b2v[t][1];
                    float a2 = ac[2] + b2v[t][2], a3 = ac[3] + b2v[t][3];
                    float vv = vA[t];
                    pw[0] += vv * a0; pw[1] += vv * a1;
                    pw[2] += vv * a2; pw[3] += vv * a3;
                    u16x4 av;
                    av.v2[0] = pk2(a0, a1);
                    av.v2[1] = pk2(a2, a3);
                    *(f16x4*)&sAG[g][i16*SAG_P + 24*(4*w + t) + 4*q4] = av.v4;
                }
                f32x4 pwv = {pw[0], pw[1], pw[2], pw[3]};
                *(f32x4*)&sWp[g][(w*16 + i16)*SWP_C + 4*q4] = pwv;
            }
            __syncthreads();   // B2: A + w partials ready
            // ======== AAT (2 pair-MFMAs/wave/set) -> G^T over A region ========
            #pragma unroll
            for (int g = 0; g < 2; ++g) {
                #pragma unroll
                for (int u0 = 0; u0 < 2; ++u0) {
                    int u = 2*w + u0;
                    int pt = 2*u + sc;
                    f16x8 af = *(const f16x8*)&sAG[g][pt*SAG_P + 24*i16 + 8*h2];
                    f32x16 gz = {0.0f};
                    f32x16 gacc = __builtin_amdgcn_mfma_f32_32x32x16_f16(af, af, gz, 0, 0, 0);
                    float gv[8];
                    #pragma unroll
                    for (int rr = 0; rr < 4; ++rr) {
                        float lo0 = gacc[rr],     hi0 = gacc[rr + 8];
                        float lo1 = gacc[rr + 4], hi1 = gacc[rr + 12];
                        float g0 = sc ? hi0 : lo0;
                        float g1 = sc ? hi1 : lo1;
                        int a0 = 4*h2 + rr;
                        int a1 = 8 + 4*h2 + rr;
                        gv[rr]     = g0 + ((i16 == a0) ? 1.0f : 0.0f);
                        gv[4 + rr] = g1 + ((i16 == a1) ? 1.0f : 0.0f);
                    }
                    u16x4 g0p, g1p;
                    g0p.v2[0] = pk2(gv[0], gv[1]); g0p.v2[1] = pk2(gv[2], gv[3]);
                    g1p.v2[0] = pk2(gv[4], gv[5]); g1p.v2[1] = pk2(gv[6], gv[7]);
                    *(f16x4*)&sAG[g][pt*SAG_P + 24*i16 + 4*h2]     = g0p.v4;
                    *(f16x4*)&sAG[g][pt*SAG_P + 24*i16 + 8 + 4*h2] = g1p.v4;
                }
            }
            // ======== r stage, both sets ========
            #pragma unroll
            for (int g = 0; g < 2; ++g) {
                float vch[8];
                {
                    const float* vp = &sZI[g][i16*SZ_P + 16 + (q4 >> 1)];
                    #pragma unroll
                    for (int c = 0; c < 8; ++c) vch[c] = vp[2*c];
                }
                float wv[8];
                {
                    f32x4 s0 = *(const f32x4*)&sWp[g][(0*16 + i16)*SWP_C + 8*sc];
                    f32x4 s1 = *(const f32x4*)&sWp[g][(1*16 + i16)*SWP_C + 8*sc];
                    f32x4 s2 = *(const f32x4*)&sWp[g][(2*16 + i16)*SWP_C + 8*sc];
                    f32x4 s3 = *(const f32x4*)&sWp[g][(3*16 + i16)*SWP_C + 8*sc];
                    f32x4 t0 = *(const f32x4*)&sWp[g][(0*16 + i16)*SWP_C + 8*sc + 4];
                    f32x4 t1 = *(const f32x4*)&sWp[g][(1*16 + i16)*SWP_C + 8*sc + 4];
                    f32x4 t2 = *(const f32x4*)&sWp[g][(2*16 + i16)*SWP_C + 8*sc + 4];
                    f32x4 t3 = *(const f32x4*)&sWp[g][(3*16 + i16)*SWP_C + 8*sc + 4];
                    #pragma unroll
                    for (int j = 0; j < 4; ++j) {
                        wv[j]     = s0[j] + s1[j] + s2[j] + s3[j];
                        wv[4 + j] = t0[j] + t1[j] + t2[j] + t3[j];
                    }
                }
                f16x2 wfp[4];
                #pragma unroll
                for (int jp = 0; jp < 4; ++jp) wfp[jp] = pk2(wv[2*jp], wv[2*jp + 1]);
                f32x4 racc = {0.f, 0.f, 0.f, 0.f};
                #pragma unroll
                for (int ch = 0; ch < 8; ++ch) {
                    f16 vvh = (f16)vch[ch];
                    f16x2 vv2; vv2.x = vvh; vv2.y = vvh;
                    u16x8 uf;
                    #pragma unroll
                    for (int jp = 0; jp < 4; ++jp) uf.v2[jp] = vv2 * wfp[jp];
                    racc = __builtin_amdgcn_mfma_f32_16x16x32_f16(w2r[ch], uf.v8, racc, 0, 0, 0);
                }
                u16x4 tv4;
                tv4.v2[0] = pk2(dreg[g][0]*racc[0], dreg[g][1]*racc[1]);
                tv4.v2[1] = pk2(dreg[g][2]*racc[2], dreg[g][3]*racc[3]);
                *(f16x4*)&sHT[g][i16*SH_P + 16*w + 4*q4] = tv4.v4;   // t overwrites h
            }
            __syncthreads();   // B4: t ready (G/aug wave-private from here)
            // ======== q stage, both sets ========
            #pragma unroll
            for (int g = 0; g < 2; ++g) {
                int ptq = 4*w + (i16 & 3);
                f16x8 tb0 = *(const f16x8*)&sHT[g][ptq*SH_P + 8*q4];
                f16x8 tb1 = *(const f16x8*)&sHT[g][ptq*SH_P + 8*q4 + 32];
                f32x4 qa = {0.f, 0.f, 0.f, 0.f};
                qa = __builtin_amdgcn_mfma_f32_16x16x32_f16(w1q[0], tb0, qa, 0, 0, 0);
                qa = __builtin_amdgcn_mfma_f32_16x16x32_f16(w1q[1], tb1, qa, 0, 0, 0);
                if (i16 < 4) {
                    #pragma unroll
                    for (int reg = 0; reg < 4; ++reg)
                        sAG[g][(4*w + i16)*SAG_P + 24*(4*q4 + reg) + 16] = (f16)qa[reg];
                }
            }
            // ======== solve G y = aug; paired across sets (fe_all2) =========
            // setprio(1): long dependent chain; with anti-phase skew the other
            // block's wave is in a throughput phase -> arbitration has bite.
            {
                __builtin_amdgcn_s_setprio(1);
                const int psl = 4*w + q4;
                float R0[17], R1[17];
                {
                    const f16* rp0 = &sAG[0][psl*SAG_P + 24*i16];
                    const f16* rp1 = &sAG[1][psl*SAG_P + 24*i16];
                    f16x8 ra0 = *(const f16x8*)&rp0[0];
                    f16x8 rb0 = *(const f16x8*)&rp0[8];
                    f16x8 ra1 = *(const f16x8*)&rp1[0];
                    f16x8 rb1 = *(const f16x8*)&rp1[8];
                    #pragma unroll
                    for (int j = 0; j < 8; ++j) {
                        R0[j] = (float)ra0[j]; R0[8+j] = (float)rb0[j];
                        R1[j] = (float)ra1[j]; R1[8+j] = (float)rb1[j];
                    }
                    R0[16] = (float)rp0[16];
                    R1[16] = (float)rp1[16];
                }
                float inv0 = 1.0f, inv1 = 1.0f;
                fe_all2<0>(R0, R1, i16, inv0, inv1);
                sKV[0][psl*SW_P + i16] = R0[16] * inv0;
                sKV[1][psl*SW_P + i16] = R1[16] * inv1;
                __builtin_amdgcn_s_setprio(0);
            }
            // (no barrier: combine reads only this wave's points; DS in-order)
            // ======== RK4 combine, both sets ========
            #pragma unroll
            for (int g = 0; g < 2; ++g) {
                f32x2 kk;
                if (g16 < 8) kk = *(const f32x2*)&sZI[g][p_cmb*SZ_P + 16 + 2*g16];
                else         kk = *(const f32x2*)&sKV[g][p_cmb*SW_P + 2*(g16 - 8)];
                if (s == 0) ar[g] = kk;
                else {
                    float wgt = (s == 3) ? 1.0f : 2.0f;
                    ar[g].x += wgt * kk.x; ar[g].y += wgt * kk.y;
                }
                f32x2 zi;
                if (s < 3) {
                    float alpha = (s < 2) ? (0.5f * dt) : dt;
                    zi.x = zc[g].x + alpha * kk.x; zi.y = zc[g].y + alpha * kk.y;
                } else {
                    float c6 = dt / 6.0f;
                    zc[g].x += c6 * ar[g].x; zc[g].y += c6 * ar[g].y;
                    zi = zc[g];
                }
                *(f32x2*)&sZI[g][p_cmb*SZ_P + 2*g16] = zi;
            }
            __syncthreads();   // B6: zI ready for next eval
        }
    }
    #pragma unroll
    for (int g = 0; g < 2; ++g) {
        int pl = pb + 16*g + p_cmb;
        if (pl < B)
            *(f32x2*)&outg[pl*32 + 2*g16] = zc[g];
    }
}

extern "C" void kernel_launch(void* const* d_in, const int* in_sizes, int n_in,
                              void* d_out, int out_size, void* d_ws, size_t ws_size,
                              hipStream_t stream) {
    (void)n_in; (void)d_ws; (void)ws_size; (void)out_size;
    const float* z  = (const float*)d_in[0];
    const float* t  = (const float*)d_in[1];
    const float* W1 = (const float*)d_in[2];
    const float* b1 = (const float*)d_in[3];
    const float* W2 = (const float*)d_in[4];
    const float* b2 = (const float*)d_in[5];
    const int*   ns = (const int*)d_in[6];
    float* out = (float*)d_out;
    const int B = in_sizes[0] / 32;
    int grid = (B + 31) / 32;
    hipLaunchKernelGGL(geo_kernel, dim3(grid), dim3(256), 0, stream,
                       z, t, W1, b1, W2, b2, ns, out, B);
}

// Round 8
// 160.768 us; speedup vs baseline: 1.0156x; 1.0156x over previous
//
#include <hip/hip_runtime.h>
#include <math.h>

// v16: v14 base (162us harness best; skew dropped -- v15 proved it null on
// harness) + ONE bounded restructure: split the GJ solve into
//   (a) G-elimination (15/16 of the chain, depends only on AAT) -- runs
//       SOURCE-INTERLEAVED with the r-stage's serial 8-MFMA accumulator
//       chain (different pipes: VALU/DPP vs MFMA), recording per-round
//       factors f[K] + pivot reciprocals;
//   (b) deferred aug column (needs q, post-B4): 16-step bcast+fma chain
//       (~160cy instead of the full 400cy solve in the post-B4 tail).
// Identical float ops in identical order -> bit-identical output.
// f/RG arrays statically indexed (rule-20-safe); VGPR growth is free
// (occupancy grid-limited at 2 blocks/CU). setprio kept on both chain
// segments (v14's measured placement).

typedef _Float16 f16;
typedef _Float16 f16x2 __attribute__((ext_vector_type(2)));
typedef _Float16 f16x4 __attribute__((ext_vector_type(4)));
typedef _Float16 f16x8 __attribute__((ext_vector_type(8)));
typedef __fp16 h16x2 __attribute__((ext_vector_type(2)));   // builtin return type
typedef float f32x2 __attribute__((ext_vector_type(2)));
typedef float f32x4 __attribute__((ext_vector_type(4)));
typedef float f32x16 __attribute__((ext_vector_type(16)));

#define SAG_P 392   // f16 point stride; row stride 24, aug col at 16
#define SZ_P  36    // f32
#define SH_P  72    // f16
#define SW_P  20    // f32
#define SWP_C 20    // f32 stride of sWp per (wave,point)

__device__ __forceinline__ float fastTanh(float x) {
    float e = exp2f(x * 2.885390081777927f);
    return 1.0f - 2.0f * __builtin_amdgcn_rcpf(1.0f + e);
}

__device__ __forceinline__ f16x2 pk2(float a, float b) {
    h16x2 p = __builtin_amdgcn_cvt_pkrtz(a, b);
    return __builtin_bit_cast(f16x2, p);
}

typedef union { f16x4 v4; f16x2 v2[2]; } u16x4;
typedef union { f16x8 v8; f16x2 v2[4]; int i32[4]; } u16x8;

// broadcast lane K of each 16-lane row via DPP row_newbcast (VALU, no DS)
template<int K>
__device__ __forceinline__ float bcf(float x) {
    int v = __builtin_amdgcn_mov_dpp(__builtin_bit_cast(int, x),
                                     0x150 | K, 0xf, 0xf, false);
    return __builtin_bit_cast(float, v);
}

// One paired G-elimination round (both sets), G columns only (j<16).
// Records f factors + pivot reciprocals for the deferred aug column.
template<int K>
__device__ __forceinline__ void roundGF(float (&R0)[16], float (&R1)[16],
                                        float (&f0)[16], float (&f1)[16],
                                        const int i16, float &inv0, float &inv1) {
    float p0 = bcf<K>(R0[K]);
    float p1 = bcf<K>(R1[K]);
    float pi0 = __builtin_amdgcn_rcpf(p0);
    float pi1 = __builtin_amdgcn_rcpf(p1);
    if (i16 == K) { inv0 = pi0; inv1 = pi1; }
    float a = (i16 == K) ? 0.0f : R0[K] * pi0;
    float b = (i16 == K) ? 0.0f : R1[K] * pi1;
    f0[K] = a; f1[K] = b;
    #pragma unroll
    for (int j = K + 1; j < 16; ++j) {
        float v0 = bcf<K>(R0[j]);
        float v1 = bcf<K>(R1[j]);
        R0[j] -= a * v0;
        R1[j] -= b * v1;
    }
}

// Interleave: per ch, {uf build + MFMA set0} round(2ch) {set1} round(2ch+1).
// MFMA accumulator chain (matrix pipe) overlaps G-elim chain (VALU pipe).
template<int CH>
__device__ __forceinline__ void rsolveCh(const f16x8 (&w2rA)[8],
    const float (&vch0)[8], const float (&vch1)[8],
    const f16x2 (&wfp0)[4], const f16x2 (&wfp1)[4],
    f32x4 &racc0, f32x4 &racc1,
    float (&R0)[16], float (&R1)[16],
    float (&f0)[16], float (&f1)[16],
    const int i16, float &inv0, float &inv1)
{
    if constexpr (CH < 8) {
        {
            f16 vvh = (f16)vch0[CH];
            f16x2 vv2; vv2.x = vvh; vv2.y = vvh;
            u16x8 uf;
            #pragma unroll
            for (int jp = 0; jp < 4; ++jp) uf.v2[jp] = vv2 * wfp0[jp];
            racc0 = __builtin_amdgcn_mfma_f32_16x16x32_f16(w2rA[CH], uf.v8, racc0, 0, 0, 0);
        }
        roundGF<2*CH>(R0, R1, f0, f1, i16, inv0, inv1);
        {
            f16 vvh = (f16)vch1[CH];
            f16x2 vv2; vv2.x = vvh; vv2.y = vvh;
            u16x8 uf;
            #pragma unroll
            for (int jp = 0; jp < 4; ++jp) uf.v2[jp] = vv2 * wfp1[jp];
            racc1 = __builtin_amdgcn_mfma_f32_16x16x32_f16(w2rA[CH], uf.v8, racc1, 0, 0, 0);
        }
        roundGF<2*CH+1>(R0, R1, f0, f1, i16, inv0, inv1);
        rsolveCh<CH+1>(w2rA, vch0, vch1, wfp0, wfp1, racc0, racc1,
                       R0, R1, f0, f1, i16, inv0, inv1);
    }
}

// Deferred aug column: identical ops/order as the original solve's j=16 lane.
template<int K>
__device__ __forceinline__ void augchain(float &a0, float &a1,
                                         const float (&f0)[16], const float (&f1)[16]) {
    if constexpr (K < 16) {
        float b0 = bcf<K>(a0);
        float b1 = bcf<K>(a1);
        a0 -= f0[K] * b0;
        a1 -= f1[K] * b1;
        augchain<K + 1>(a0, a1, f0, f1);
    }
}

__global__ __launch_bounds__(256, 1)
void geo_kernel(const float* __restrict__ zin, const float* __restrict__ tg,
                const float* __restrict__ W1g, const float* __restrict__ b1g,
                const float* __restrict__ W2g, const float* __restrict__ b2g,
                const int* __restrict__ nsg, float* __restrict__ outg, int B)
{
    __shared__ __align__(16) f16   sAG[2][16 * SAG_P];      // A, then G (+aug)
    __shared__ __align__(16) f16   sHT[2][16 * SH_P];       // h, later t
    __shared__ __align__(16) float sZI[2][16 * SZ_P];
    __shared__ __align__(16) float sKV[2][16 * SW_P];
    __shared__ __align__(16) float sWp[2][4 * 16 * SWP_C];  // w partials per wave

    const int tid = threadIdx.x;
    const int w = tid >> 6;
    const int l = tid & 63;
    const int i16 = l & 15, q4 = l >> 4, h2 = l >> 5, sc = q4 & 1;

    // ---------------- hoisted weight fragments (quarter per wave) ----------
    f16x8 w2a[4][2];   // A-stage A-op: W2^T[e=i16+16(4w+t)][k=8q4+j+32ch]
    #pragma unroll
    for (int t = 0; t < 4; ++t)
        #pragma unroll
        for (int ch = 0; ch < 2; ++ch)
            #pragma unroll
            for (int j = 0; j < 8; ++j)
                w2a[t][ch][j] = (f16)W2g[(8*q4 + j + 32*ch)*256 + i16 + 16*(4*w + t)];

    f16x8 w2r[8];      // r-stage A-op: W2[n=i16+16w][e=8q4+j+32ch]
    #pragma unroll
    for (int ch = 0; ch < 8; ++ch)
        #pragma unroll
        for (int j = 0; j < 8; ++j)
            w2r[ch][j] = (f16)W2g[(i16 + 16*w)*256 + 8*q4 + j + 32*ch];

    f16x8 w1h;         // H-stage A-op: W1^T[n=i16+16w][x=8q4+j], zero-pad k>=16
    #pragma unroll
    for (int j = 0; j < 8; ++j) {
        int k = 8*q4 + j;
        w1h[j] = (k < 16) ? (f16)W1g[k*64 + i16 + 16*w] : (f16)0.0f;
    }

    f16x8 w1q[2];      // q-stage A-op: W1[i=i16][n=8q4+j+32ch]
    #pragma unroll
    for (int ch = 0; ch < 2; ++ch)
        #pragma unroll
        for (int j = 0; j < 8; ++j)
            w1q[ch][j] = (f16)W1g[i16*64 + 8*q4 + j + 32*ch];

    float b2v[4][4];   // b2[e = 16*(4w+t) + 4q4+reg]
    #pragma unroll
    for (int t = 0; t < 4; ++t)
        #pragma unroll
        for (int reg = 0; reg < 4; ++reg)
            b2v[t][reg] = b2g[16*(4*w + t) + 4*q4 + reg];
    float b1v[4];      // b1[n = 16w + 4q4+reg]
    #pragma unroll
    for (int reg = 0; reg < 4; ++reg) b1v[reg] = b1g[16*w + 4*q4 + reg];

    // ---------------- RK4 state: thread owns points (g,tid>>4) ------------
    const int pb = blockIdx.x * 32;
    const int p_cmb = tid >> 4;            // == 4w + q4
    const int g16 = tid & 15;
    f32x2 zc[2], ar[2];
    #pragma unroll
    for (int g = 0; g < 2; ++g) {
        int pl = pb + 16*g + p_cmb;
        int pg = (pl < B) ? pl : (B - 1);
        zc[g] = *(const f32x2*)&zin[pg*32 + 2*g16];
        *(f32x2*)&sZI[g][p_cmb*SZ_P + 2*g16] = zc[g];
    }
    __syncthreads();

    const float tv = tg[0];
    const int nst = nsg[0];
    const float dt = tv / (float)nst;

    const int xmask = (q4 >= 2) ? 0 : -1;

    #pragma unroll 1
    for (int st = 0; st < nst; ++st) {
        #pragma unroll 1
        for (int s = 0; s < 4; ++s) {
            float dreg[2][4];
            // ======== X-load + H, both sets ========
            #pragma unroll
            for (int g = 0; g < 2; ++g) {
                u16x8 xf;
                {
                    f32x4 xa = *(const f32x4*)&sZI[g][i16*SZ_P + 8*sc];
                    f32x4 xb = *(const f32x4*)&sZI[g][i16*SZ_P + 8*sc + 4];
                    xf.v2[0] = pk2(xa[0], xa[1]);
                    xf.v2[1] = pk2(xa[2], xa[3]);
                    xf.v2[2] = pk2(xb[0], xb[1]);
                    xf.v2[3] = pk2(xb[2], xb[3]);
                    #pragma unroll
                    for (int jp = 0; jp < 4; ++jp) xf.i32[jp] &= xmask;
                }
                f32x4 hc = {0.f, 0.f, 0.f, 0.f};
                hc = __builtin_amdgcn_mfma_f32_16x16x32_f16(w1h, xf.v8, hc, 0, 0, 0);
                float hv[4];
                #pragma unroll
                for (int reg = 0; reg < 4; ++reg) {
                    hv[reg] = fastTanh(hc[reg] + b1v[reg]);
                    dreg[g][reg] = hv[reg]*hv[reg] - 1.0f;
                }
                u16x4 hv4;
                hv4.v2[0] = pk2(hv[0], hv[1]);
                hv4.v2[1] = pk2(hv[2], hv[3]);
                *(f16x4*)&sHT[g][i16*SH_P + 16*w + 4*q4] = hv4.v4;
            }
            __syncthreads();   // B1: h ready
            // ======== A stage, both sets ========
            #pragma unroll
            for (int g = 0; g < 2; ++g) {
                f32x4 vA = *(const f32x4*)&sZI[g][i16*SZ_P + 16 + 4*w];
                f16x8 hf0 = *(const f16x8*)&sHT[g][i16*SH_P + 8*q4];
                f16x8 hf1 = *(const f16x8*)&sHT[g][i16*SH_P + 8*q4 + 32];
                float pw[4] = {0.f, 0.f, 0.f, 0.f};
                #pragma unroll
                for (int t = 0; t < 4; ++t) {
                    f32x4 ac = {0.f, 0.f, 0.f, 0.f};
                    ac = __builtin_amdgcn_mfma_f32_16x16x32_f16(w2a[t][0], hf0, ac, 0, 0, 0);
                    ac = __builtin_amdgcn_mfma_f32_16x16x32_f16(w2a[t][1], hf1, ac, 0, 0, 0);
                    float a0 = ac[0] + b2v[t][0], a1 = ac[1] + b2v[t][1];
                    float a2 = ac[2] + b2v[t][2], a3 = ac[3] + b2v[t][3];
                    float vv = vA[t];
                    pw[0] += vv * a0; pw[1] += vv * a1;
                    pw[2] += vv * a2; pw[3] += vv * a3;
                    u16x4 av;
                    av.v2[0] = pk2(a0, a1);
                    av.v2[1] = pk2(a2, a3);
                    *(f16x4*)&sAG[g][i16*SAG_P + 24*(4*w + t) + 4*q4] = av.v4;
                }
                f32x4 pwv = {pw[0], pw[1], pw[2], pw[3]};
                *(f32x4*)&sWp[g][(w*16 + i16)*SWP_C + 4*q4] = pwv;
            }
            __syncthreads();   // B2: A + w partials ready
            // ======== AAT (2 pair-MFMAs/wave/set) -> G^T over A region ========
            #pragma unroll
            for (int g = 0; g < 2; ++g) {
                #pragma unroll
                for (int u0 = 0; u0 < 2; ++u0) {
                    int u = 2*w + u0;
                    int pt = 2*u + sc;
                    f16x8 af = *(const f16x8*)&sAG[g][pt*SAG_P + 24*i16 + 8*h2];
                    f32x16 gz = {0.0f};
                    f32x16 gacc = __builtin_amdgcn_mfma_f32_32x32x16_f16(af, af, gz, 0, 0, 0);
                    float gv[8];
                    #pragma unroll
                    for (int rr = 0; rr < 4; ++rr) {
                        float lo0 = gacc[rr],     hi0 = gacc[rr + 8];
                        float lo1 = gacc[rr + 4], hi1 = gacc[rr + 12];
                        float g0 = sc ? hi0 : lo0;
                        float g1 = sc ? hi1 : lo1;
                        int a0 = 4*h2 + rr;
                        int a1 = 8 + 4*h2 + rr;
                        gv[rr]     = g0 + ((i16 == a0) ? 1.0f : 0.0f);
                        gv[4 + rr] = g1 + ((i16 == a1) ? 1.0f : 0.0f);
                    }
                    u16x4 g0p, g1p;
                    g0p.v2[0] = pk2(gv[0], gv[1]); g0p.v2[1] = pk2(gv[2], gv[3]);
                    g1p.v2[0] = pk2(gv[4], gv[5]); g1p.v2[1] = pk2(gv[6], gv[7]);
                    *(f16x4*)&sAG[g][pt*SAG_P + 24*i16 + 4*h2]     = g0p.v4;
                    *(f16x4*)&sAG[g][pt*SAG_P + 24*i16 + 8 + 4*h2] = g1p.v4;
                }
            }
            // ======== r-prep (both sets) ========
            const int psl = 4*w + q4;
            float vchA[2][8];
            f16x2 wfpA[2][4];
            #pragma unroll
            for (int g = 0; g < 2; ++g) {
                const float* vp = &sZI[g][i16*SZ_P + 16 + (q4 >> 1)];
                #pragma unroll
                for (int c = 0; c < 8; ++c) vchA[g][c] = vp[2*c];
                float wv[8];
                {
                    f32x4 s0 = *(const f32x4*)&sWp[g][(0*16 + i16)*SWP_C + 8*sc];
                    f32x4 s1 = *(const f32x4*)&sWp[g][(1*16 + i16)*SWP_C + 8*sc];
                    f32x4 s2 = *(const f32x4*)&sWp[g][(2*16 + i16)*SWP_C + 8*sc];
                    f32x4 s3 = *(const f32x4*)&sWp[g][(3*16 + i16)*SWP_C + 8*sc];
                    f32x4 t0 = *(const f32x4*)&sWp[g][(0*16 + i16)*SWP_C + 8*sc + 4];
                    f32x4 t1 = *(const f32x4*)&sWp[g][(1*16 + i16)*SWP_C + 8*sc + 4];
                    f32x4 t2 = *(const f32x4*)&sWp[g][(2*16 + i16)*SWP_C + 8*sc + 4];
                    f32x4 t3 = *(const f32x4*)&sWp[g][(3*16 + i16)*SWP_C + 8*sc + 4];
                    #pragma unroll
                    for (int j = 0; j < 4; ++j) {
                        wv[j]     = s0[j] + s1[j] + s2[j] + s3[j];
                        wv[4 + j] = t0[j] + t1[j] + t2[j] + t3[j];
                    }
                }
                #pragma unroll
                for (int jp = 0; jp < 4; ++jp) wfpA[g][jp] = pk2(wv[2*jp], wv[2*jp + 1]);
            }
            // ---- load G rows (wave-private; DS in-order after AAT writes)
            float RG0[16], RG1[16];
            {
                const f16* rp0 = &sAG[0][psl*SAG_P + 24*i16];
                const f16* rp1 = &sAG[1][psl*SAG_P + 24*i16];
                f16x8 ra0 = *(const f16x8*)&rp0[0];
                f16x8 rb0 = *(const f16x8*)&rp0[8];
                f16x8 ra1 = *(const f16x8*)&rp1[0];
                f16x8 rb1 = *(const f16x8*)&rp1[8];
                #pragma unroll
                for (int j = 0; j < 8; ++j) {
                    RG0[j] = (float)ra0[j]; RG0[8+j] = (float)rb0[j];
                    RG1[j] = (float)ra1[j]; RG1[8+j] = (float)rb1[j];
                }
            }
            // ======== interleaved: r MFMA chain (matrix pipe) || G-elim
            //          (VALU/DPP pipe), both sets paired ========
            f32x4 racc0 = {0.f, 0.f, 0.f, 0.f};
            f32x4 racc1 = {0.f, 0.f, 0.f, 0.f};
            float fA0[16], fA1[16];
            float inv0 = 1.0f, inv1 = 1.0f;
            __builtin_amdgcn_s_setprio(1);
            rsolveCh<0>(w2r, vchA[0], vchA[1], wfpA[0], wfpA[1],
                        racc0, racc1, RG0, RG1, fA0, fA1, i16, inv0, inv1);
            __builtin_amdgcn_s_setprio(0);
            // ---- t writes, both sets
            {
                u16x4 tv4;
                tv4.v2[0] = pk2(dreg[0][0]*racc0[0], dreg[0][1]*racc0[1]);
                tv4.v2[1] = pk2(dreg[0][2]*racc0[2], dreg[0][3]*racc0[3]);
                *(f16x4*)&sHT[0][i16*SH_P + 16*w + 4*q4] = tv4.v4;
                tv4.v2[0] = pk2(dreg[1][0]*racc1[0], dreg[1][1]*racc1[1]);
                tv4.v2[1] = pk2(dreg[1][2]*racc1[2], dreg[1][3]*racc1[3]);
                *(f16x4*)&sHT[1][i16*SH_P + 16*w + 4*q4] = tv4.v4;
            }
            __syncthreads();   // B4: t ready (G/aug wave-private from here)
            // ======== q stage, both sets ========
            #pragma unroll
            for (int g = 0; g < 2; ++g) {
                int ptq = 4*w + (i16 & 3);
                f16x8 tb0 = *(const f16x8*)&sHT[g][ptq*SH_P + 8*q4];
                f16x8 tb1 = *(const f16x8*)&sHT[g][ptq*SH_P + 8*q4 + 32];
                f32x4 qa = {0.f, 0.f, 0.f, 0.f};
                qa = __builtin_amdgcn_mfma_f32_16x16x32_f16(w1q[0], tb0, qa, 0, 0, 0);
                qa = __builtin_amdgcn_mfma_f32_16x16x32_f16(w1q[1], tb1, qa, 0, 0, 0);
                if (i16 < 4) {
                    #pragma unroll
                    for (int reg = 0; reg < 4; ++reg)
                        sAG[g][(4*w + i16)*SAG_P + 24*(4*q4 + reg) + 16] = (f16)qa[reg];
                }
            }
            // ======== deferred aug column + y (short chain) ========
            {
                float a0 = (float)sAG[0][psl*SAG_P + 24*i16 + 16];
                float a1 = (float)sAG[1][psl*SAG_P + 24*i16 + 16];
                __builtin_amdgcn_s_setprio(1);
                augchain<0>(a0, a1, fA0, fA1);
                sKV[0][psl*SW_P + i16] = a0 * inv0;
                sKV[1][psl*SW_P + i16] = a1 * inv1;
                __builtin_amdgcn_s_setprio(0);
            }
            // (no barrier: combine reads only this wave's points; DS in-order)
            // ======== RK4 combine, both sets ========
            #pragma unroll
            for (int g = 0; g < 2; ++g) {
                f32x2 kk;
                if (g16 < 8) kk = *(const f32x2*)&sZI[g][p_cmb*SZ_P + 16 + 2*g16];
                else         kk = *(const f32x2*)&sKV[g][p_cmb*SW_P + 2*(g16 - 8)];
                if (s == 0) ar[g] = kk;
                else {
                    float wgt = (s == 3) ? 1.0f : 2.0f;
                    ar[g].x += wgt * kk.x; ar[g].y += wgt * kk.y;
                }
                f32x2 zi;
                if (s < 3) {
                    float alpha = (s < 2) ? (0.5f * dt) : dt;
                    zi.x = zc[g].x + alpha * kk.x; zi.y = zc[g].y + alpha * kk.y;
                } else {
                    float c6 = dt / 6.0f;
                    zc[g].x += c6 * ar[g].x; zc[g].y += c6 * ar[g].y;
                    zi = zc[g];
                }
                *(f32x2*)&sZI[g][p_cmb*SZ_P + 2*g16] = zi;
            }
            __syncthreads();   // B6: zI ready for next eval
        }
    }
    #pragma unroll
    for (int g = 0; g < 2; ++g) {
        int pl = pb + 16*g + p_cmb;
        if (pl < B)
            *(f32x2*)&outg[pl*32 + 2*g16] = zc[g];
    }
}

extern "C" void kernel_launch(void* const* d_in, const int* in_sizes, int n_in,
                              void* d_out, int out_size, void* d_ws, size_t ws_size,
                              hipStream_t stream) {
    (void)n_in; (void)d_ws; (void)ws_size; (void)out_size;
    const float* z  = (const float*)d_in[0];
    const float* t  = (const float*)d_in[1];
    const float* W1 = (const float*)d_in[2];
    const float* b1 = (const float*)d_in[3];
    const float* W2 = (const float*)d_in[4];
    const float* b2 = (const float*)d_in[5];
    const int*   ns = (const int*)d_in[6];
    float* out = (float*)d_out;
    const int B = in_sizes[0] / 32;
    int grid = (B + 31) / 32;
    hipLaunchKernelGGL(geo_kernel, dim3(grid), dim3(256), 0, stream,
                       z, t, W1, b1, W2, b2, ns, out, B);
}